// Round 7
// baseline (1499.137 us; speedup 1.0000x reference)
//
#include <hip/hip_runtime.h>
#include <cstddef>

// Problem constants (reference: B=8, S=512, E=128, H=512, ENC=128)
#define BB 8
#define SS 512
#define EE 128
#define HH 512
#define ENC 128

// ---------------------------------------------------------------------------
// Bit-exact emulation of XLA CPU's EmitTanh (verified bitwise r6..r15).
// All ops rn, NON-fused. __f*_rn intrinsics block compiler contraction.
// NOTE (r8): packed v_pk_* fp32 is NOT bit-identical on gfx950 — scalar only.
// ---------------------------------------------------------------------------
__device__ __forceinline__ float xla_tanhf(float x) {
    const float cx = fminf(fmaxf(x, -9.0f), 9.0f);
    const float x2 = __fmul_rn(cx, cx);
    float p = -2.76076847742355e-16f;
    p = __fadd_rn(__fmul_rn(p, x2), 2.00018790482477e-13f);
    p = __fadd_rn(__fmul_rn(p, x2), -8.60467152213735e-11f);
    p = __fadd_rn(__fmul_rn(p, x2), 5.12229709037114e-08f);
    p = __fadd_rn(__fmul_rn(p, x2), 1.48572235717979e-05f);
    p = __fadd_rn(__fmul_rn(p, x2), 6.37261928875436e-04f);
    p = __fadd_rn(__fmul_rn(p, x2), 4.89352455891786e-03f);
    const float num = __fmul_rn(cx, p);
    float q = 1.19825839466702e-06f;
    q = __fadd_rn(__fmul_rn(q, x2), 1.18534705686654e-04f);
    q = __fadd_rn(__fmul_rn(q, x2), 2.26843463243900e-03f);
    q = __fadd_rn(__fmul_rn(q, x2), 4.89352518554385e-03f);
    const float r = __fdiv_rn(num, q);
    return (fabsf(x) < 0.0004f) ? x : r;
}

// Map a packed chunk-row m -> global action row:
//   b = m >> chsh (CH = chm1+1), global row = b*SS + i0 + (m & chm1)
__device__ __forceinline__ int arow_map(int m, int chm1, int chsh, int i0) {
    return ((m >> chsh) * SS) + i0 + (m & chm1);
}

// ---------------------------------------------------------------------------
// Tiled GEMM, bitwise-preserving XLA-CPU dot semantics (VERIFIED r6..r22 —
// scalar v_mul/v_add only). K-chain: one accumulator per element, k0 tiles
// ascend, inner k ascends — DO NOT TOUCH.
//
// r22 (KEPT VERBATIM — measured AT the scalar-VALU floor: 433 us/chunk vs
// 437 us computed; bank conflicts 5.87e7 -> 8.4e6):
//   * LDS rows padded 128 -> 132 floats (4-way -> 2-way write conflicts).
//   * b-columns strided: thread tx reads Bs[k][tx*4], Bs[k][64+tx*4].
//     Epilogue remapped to match: j<4 -> c=tx*4+j, j>=4 -> c=64+tx*4+(j-4).
//
// TRANSP=1 (GEMM2 only): block bx covers B-rows o = d*128+e with
// d in [16*bd,16*bd+16), e in [8*be,8*be+8)  (bd=bx>>4, be=bx&15).
// Epilogue stores the d-INTERLEAVED layout:
//   Wa4[m][(d>>2)*128 + e] as float4 component (d&3)
// so the scan's quarter loads are lane-consecutive float4 (r15-proven).
// ---------------------------------------------------------------------------
template <int ACT, int MAPROW, int TRANSP>
__global__ __launch_bounds__(256) void gemm_nt(const float* __restrict__ A,
                                               const float* __restrict__ Bm,
                                               const float* __restrict__ bias,
                                               float* __restrict__ C,
                                               int N, int K,
                                               int chm1, int chsh, int i0) {
    __shared__ float As[16][132];   // +4 pad: kills 4-way write conflicts
    __shared__ float Bs[16][132];

    const int tid = threadIdx.x;
    const int tx = tid & 15;   // n-direction (8 cols each, strided mapping)
    const int ty = tid >> 4;   // m-direction (8 rows each)
    const int n0 = blockIdx.x * 128;
    const int m0 = blockIdx.y * 128;
    const int bd = blockIdx.x >> 4;   // TRANSP: d-tile (0..7)
    const int be = blockIdx.x & 15;   // TRANSP: e-tile (0..15)

    const int lr = tid >> 2;          // 0..63 (row within tile)
    const int lc = (tid & 3) << 2;    // 0,4,8,12 (col within K-tile)

    const int ga0 = MAPROW ? arow_map(m0 + lr, chm1, chsh, i0) : (m0 + lr);
    const int ga1 = MAPROW ? arow_map(m0 + lr + 64, chm1, chsh, i0) : (m0 + lr + 64);

    // B-row indices for the two loader rows (identity unless TRANSP)
    const int r0 = lr, r1 = lr + 64;
    const int gb0 = TRANSP ? ((bd * 16 + (r0 >> 3)) * 128 + be * 8 + (r0 & 7))
                           : (n0 + r0);
    const int gb1 = TRANSP ? ((bd * 16 + (r1 >> 3)) * 128 + be * 8 + (r1 & 7))
                           : (n0 + r1);

    float acc[8][8];
#pragma unroll
    for (int i = 0; i < 8; ++i)
#pragma unroll
        for (int j = 0; j < 8; ++j) acc[i][j] = 0.f;

    for (int k0 = 0; k0 < K; k0 += 16) {
        const float4 a0 = *(const float4*)(A + (size_t)ga0 * K + (k0 + lc));
        const float4 a1 = *(const float4*)(A + (size_t)ga1 * K + (k0 + lc));
        const float4 b0 = *(const float4*)(Bm + (size_t)gb0 * K + (k0 + lc));
        const float4 b1 = *(const float4*)(Bm + (size_t)gb1 * K + (k0 + lc));

        __syncthreads();  // previous iteration's compute done before overwrite

        As[lc + 0][lr] = a0.x; As[lc + 1][lr] = a0.y;
        As[lc + 2][lr] = a0.z; As[lc + 3][lr] = a0.w;
        As[lc + 0][lr + 64] = a1.x; As[lc + 1][lr + 64] = a1.y;
        As[lc + 2][lr + 64] = a1.z; As[lc + 3][lr + 64] = a1.w;
        Bs[lc + 0][lr] = b0.x; Bs[lc + 1][lr] = b0.y;
        Bs[lc + 2][lr] = b0.z; Bs[lc + 3][lr] = b0.w;
        Bs[lc + 0][lr + 64] = b1.x; Bs[lc + 1][lr + 64] = b1.y;
        Bs[lc + 2][lr + 64] = b1.z; Bs[lc + 3][lr + 64] = b1.w;

        __syncthreads();

#pragma unroll
        for (int k = 0; k < 16; ++k) {   // ascending k within tile
            const float4 av0 = *(const float4*)&As[k][ty * 8];
            const float4 av1 = *(const float4*)&As[k][ty * 8 + 4];
            const float4 bv0 = *(const float4*)&Bs[k][tx * 4];        // strided
            const float4 bv1 = *(const float4*)&Bs[k][64 + tx * 4];   // strided
            const float a[8] = {av0.x, av0.y, av0.z, av0.w, av1.x, av1.y, av1.z, av1.w};
            const float b[8] = {bv0.x, bv0.y, bv0.z, bv0.w, bv1.x, bv1.y, bv1.z, bv1.w};
#pragma unroll
            for (int i = 0; i < 8; ++i)
#pragma unroll
                for (int j = 0; j < 8; ++j)
                    acc[i][j] = __fadd_rn(acc[i][j], __fmul_rn(a[i], b[j]));
        }
    }

    // epilogue: + bias (after full k-chain), optional XLA tanh, store.
    // acc[i][j] is output col c = (j<4) ? tx*4+j : 64+tx*4+(j-4) of the tile.
#pragma unroll
    for (int i = 0; i < 8; ++i) {
        const int m = m0 + ty * 8 + i;
        if (TRANSP) {
            // in-tile col c -> o = d*128+ee, d = bd*16+(c>>3), ee = be*8+(c&7)
            // d-interleaved store: C[m][((d>>2)*128 + ee)*4 + (d&3)]
#pragma unroll
            for (int j = 0; j < 8; ++j) {
                const int c = (j < 4) ? (tx * 4 + j) : (64 + tx * 4 + (j - 4));
                const int d = bd * 16 + (c >> 3);
                const int ee = be * 8 + (c & 7);
                const int o = d * 128 + ee;
                const float v = __fadd_rn(acc[i][j], bias[o]);
                C[(size_t)m * N + ((size_t)(d >> 2) * 128 + ee) * 4 + (d & 3)] = v;
            }
        } else {
            float v[8];
#pragma unroll
            for (int j = 0; j < 4; ++j) {
                const int n = n0 + tx * 4 + j;
                v[j] = __fadd_rn(acc[i][j], bias[n]);
                if (ACT) v[j] = xla_tanhf(v[j]);
            }
#pragma unroll
            for (int j = 4; j < 8; ++j) {
                const int n = n0 + 64 + tx * 4 + (j - 4);
                v[j] = __fadd_rn(acc[i][j], bias[n]);
                if (ACT) v[j] = xla_tanhf(v[j]);
            }
            *(float4*)(C + (size_t)m * N + (n0 + tx * 4)) =
                make_float4(v[0], v[1], v[2], v[3]);
            *(float4*)(C + (size_t)m * N + (n0 + 64 + tx * 4)) =
                make_float4(v[4], v[5], v[6], v[7]);
        }
    }
}

// ---------------------------------------------------------------------------
// r21-proven non-draining workgroup barrier (validated correct, absmax 0.0):
// __syncthreads() emits `s_waitcnt vmcnt(0) lgkmcnt(0)` before s_barrier,
// draining the whole prefetch queue each step and re-exposing load latency
// per step. The scan's ping-pong only needs LDS ordering:
//     ds_write et -> s_waitcnt lgkmcnt(0) -> s_barrier
// VGPR-targeted prefetch loads are guarded by the compiler's precise
// vmcnt(N) waits at their consume sites.
// ---------------------------------------------------------------------------
__device__ __forceinline__ void scan_barrier_nodrain() {
    asm volatile("s_waitcnt lgkmcnt(0)" ::: "memory");
    __builtin_amdgcn_s_barrier();
    asm volatile("" ::: "memory");
}

// ---------------------------------------------------------------------------
// Sequential attractor scan — r23: prefetch distance SIX quarters.
//   * Rationale: r22 (distance 3) leaves ~150-300 cyc of L3 latency exposed
//     per quarter (cover ~384 cyc < L3 ~500-700 cyc) -> ~2350 cyc/step vs
//     ~600 structural floor. Distance 8 (r20) broke the vmcnt cap (64
//     outstanding > 63 -> stall at load ISSUE). Distance 6 = 48 outstanding
//     (under cap) with ~640+ cyc cover.
//   * 6 named buffers b0..b5; buffer for global quarter t is t mod 6;
//     period = 3 steps, implemented as a 3-step unrolled body so every
//     index is static (rule #20). Consume-then-refill: refill target
//     (t+6) mod 6 = t mod 6 = the buffer just consumed.
//   * Clamped straight-line prefetch (r16-proven) — no workspace pad.
//   * Non-drain barrier (r21-proven).
// Chain is op-for-op the verified sequence: ONE accumulator, strictly
// ascending d (q asc, dq asc, x,y,z,w = d..d+3), non-fused rn ops — bitwise
// contract. VGPR: 6x8 float4 = 192 buffer + ~30 misc ≈ 225 (1 block/CU,
// full 512 budget -> no spill expected; VGPR_Count < 192 = spill signature).
// ---------------------------------------------------------------------------
#define SCAN_CQ6(Q, BUF)                                                    \
    {                                                                       \
        /* consume quarter Q: d = 32Q .. 32Q+31, strictly ascending */      \
        _Pragma("unroll")                                                   \
        for (int dq = 0; dq < 8; ++dq) {                                    \
            const float4 t4 = *(const float4*)&et[s][(Q) * 32 + dq * 4];    \
            const float4 wv = BUF[dq]; /* W[d..d+3][e], d = 32Q+4dq */      \
            sum = __fadd_rn(sum, __fmul_rn(t4.x, wv.x));                    \
            sum = __fadd_rn(sum, __fmul_rn(t4.y, wv.y));                    \
            sum = __fadd_rn(sum, __fmul_rn(t4.z, wv.z));                    \
            sum = __fadd_rn(sum, __fmul_rn(t4.w, wv.w));                    \
        }                                                                   \
        /* refill BUF with quarter t+6 (clamped, straight-line) */          \
        const int pf = (ii - start) * 4 + (Q) + 6;                          \
        const int pfc = (pf < nq) ? pf : (nq - 1); /* uniform select */     \
        const float4* P4 = Wb4 + (size_t)(start + (pfc >> 2)) * 4096        \
                               + (size_t)(pfc & 3) * 1024 + e;              \
        _Pragma("unroll")                                                   \
        for (int u = 0; u < 8; ++u) BUF[u] = P4[u * 128];                   \
        asm volatile("" ::: "memory");                                      \
    }

#define SCAN_STEP6(QA, QB, QC, QD)                                          \
    {                                                                       \
        float sum = 0.f; /* ONE accumulator, ascending d across quarters */ \
        SCAN_CQ6(0, QA)                                                     \
        SCAN_CQ6(1, QB)                                                     \
        SCAN_CQ6(2, QC)                                                     \
        SCAN_CQ6(3, QD)                                                     \
        const float v = fminf(fmaxf(sum, -5.f), 5.f); /* jnp.clip */        \
        out[((size_t)b * SS + (i0 + ii)) * ENC + e] = v;                    \
        et[s ^ 1][e] = v;                                                   \
        scan_barrier_nodrain(); /* publishes et[s^1]; keeps vmcnt queue */  \
        s ^= 1;                                                             \
        ++ii;                                                               \
    }

__global__ __launch_bounds__(128, 1) void scan_kernel(const float* __restrict__ Wa,
                                                      const float* __restrict__ e0,
                                                      float* __restrict__ et_state,
                                                      float* __restrict__ out,
                                                      int i0, int CH) {
    __shared__ float et[2][128];
    const int b = blockIdx.x;
    const int e = threadIdx.x;  // 0..127

    int s = 0;
    if (i0 == 0) {
        const float v = e0[e];
        et[0][e] = v;
        out[(size_t)b * SS * ENC + e] = v;
    } else {
        et[0][e] = et_state[b * 128 + e];
    }
    __syncthreads();   // once, before the pipeline — drain is harmless here

    const int start = (i0 == 0) ? 1 : 0;
    const float4* Wb4 = (const float4*)(Wa + (size_t)b * CH * (ENC * ENC));
    const int nq = (CH - start) * 4;   // total quarter-tiles this launch
    // step stride in float4: ENC*ENC/4 = 4096; quarter stride: 8*128 = 1024

    // 6 quarter buffers x 8 float4 = 192 VGPRs; preload quarters 0..5
    // (1.5 steps in flight; 48 outstanding loads at steady state).
    float4 b0[8], b1[8], b2[8], b3[8], b4[8], b5[8];
    {
        const float4* S4 = Wb4 + (size_t)start * 4096 + e;
#pragma unroll
        for (int u = 0; u < 8; ++u) b0[u] = S4[u * 128];
#pragma unroll
        for (int u = 0; u < 8; ++u) b1[u] = S4[(8 + u) * 128];
#pragma unroll
        for (int u = 0; u < 8; ++u) b2[u] = S4[(16 + u) * 128];
#pragma unroll
        for (int u = 0; u < 8; ++u) b3[u] = S4[(24 + u) * 128];
#pragma unroll
        for (int u = 0; u < 8; ++u) b4[u] = S4[(32 + u) * 128];
#pragma unroll
        for (int u = 0; u < 8; ++u) b5[u] = S4[(40 + u) * 128];
    }
    asm volatile("" ::: "memory");  // loads pinned before first chain

    int ii = start;
    const int triples = (CH - start) / 3;
    const int rem = (CH - start) % 3;

    // Buffer schedule (t = global quarter counter, buffer = t mod 6):
    //   step 3p+0: t=12p+0..3   -> b0,b1,b2,b3
    //   step 3p+1: t=12p+4..7   -> b4,b5,b0,b1
    //   step 3p+2: t=12p+8..11  -> b2,b3,b4,b5
    for (int p = 0; p < triples; ++p) {
        SCAN_STEP6(b0, b1, b2, b3)
        SCAN_STEP6(b4, b5, b0, b1)
        SCAN_STEP6(b2, b3, b4, b5)
    }
    // Remainder (<=2 steps): same static bodies; refills are clamped so the
    // over-issue past nq is safe and the values are never consumed.
    if (rem >= 1) { SCAN_STEP6(b0, b1, b2, b3) }
    if (rem >= 2) { SCAN_STEP6(b4, b5, b0, b1) }

    et_state[b * 128 + e] = et[s][e];
}

// ---------------------------------------------------------------------------
extern "C" void kernel_launch(void* const* d_in, const int* in_sizes, int n_in,
                              void* d_out, int out_size, void* d_ws, size_t ws_size,
                              hipStream_t stream) {
    const float* A  = (const float*)d_in[0];  // (B,S,E)   = (8,512,128) fp32
    const float* W1 = (const float*)d_in[1];  // (H,E)     = (512,128)  fp32
    const float* b1 = (const float*)d_in[2];  // (H,)      fp32
    const float* W2 = (const float*)d_in[3];  // (ENC*ENC,H) = (16384,512) fp32
    const float* b2 = (const float*)d_in[4];  // (ENC*ENC,) fp32
    const float* e0 = (const float*)d_in[5];  // (1,ENC)   fp32
    float* out = (float*)d_out;               // (B,S,ENC) fp32

    // Serial r16 schedule (known-good base).
    // Pick the largest chunk CH (steps) whose fp32 workspace fits ws_size.
    // ws layout: [et_state 4KB][hidden_c Mc*512 f32][Wa_c Mc*16384 f32]
    int CH = 16;
    for (int c = 512; c >= 16; c >>= 1) {
        const size_t Mc = (size_t)BB * c;
        const size_t need = 4096 + Mc * HH * sizeof(float) +
                            Mc * (size_t)(ENC * ENC) * sizeof(float);
        if (need <= ws_size) { CH = c; break; }
    }
    const int Mc = BB * CH;
    int chsh = 0;
    while ((1 << chsh) < CH) ++chsh;
    const int chm1 = CH - 1;

    float* et_state = (float*)d_ws;
    float* hidden   = (float*)((char*)d_ws + 4096);
    float* Wa       = hidden + (size_t)Mc * HH;   // d-interleaved layout (Wa4)

    for (int i0 = 0; i0 < SS; i0 += CH) {
        // GEMM1: hidden_c = tanh(A[chunk rows] @ W1^T + b1)  [Mc x 512, K=128]
        dim3 g1(HH / 128, Mc / 128);
        gemm_nt<1, 1, 0><<<g1, 256, 0, stream>>>(A, W1, b1, hidden, HH, EE,
                                                 chm1, chsh, i0);
        // GEMM2: Wa4_c = (hidden_c @ W2^T + b2) stored d-interleaved
        dim3 g2((ENC * ENC) / 128, Mc / 128);
        gemm_nt<0, 0, 1><<<g2, 256, 0, stream>>>(hidden, W2, b2, Wa, ENC * ENC,
                                                 HH, 0, 0, 0);
        // scan this chunk (one workgroup per batch; fp32 state in ws)
        scan_kernel<<<BB, 128, 0, stream>>>(Wa, e0, et_state, out, i0, CH);
    }
}

// Round 8
// 1480.667 us; speedup vs baseline: 1.0125x; 1.0125x over previous
//
#include <hip/hip_runtime.h>
#include <cstddef>

// Problem constants (reference: B=8, S=512, E=128, H=512, ENC=128)
#define BB 8
#define SS 512
#define EE 128
#define HH 512
#define ENC 128

// ---------------------------------------------------------------------------
// Bit-exact emulation of XLA CPU's EmitTanh (verified bitwise r6..r15).
// All ops rn, NON-fused. __f*_rn intrinsics block compiler contraction.
// NOTE (r8): packed v_pk_* fp32 is NOT bit-identical on gfx950 — scalar only.
// ---------------------------------------------------------------------------
__device__ __forceinline__ float xla_tanhf(float x) {
    const float cx = fminf(fmaxf(x, -9.0f), 9.0f);
    const float x2 = __fmul_rn(cx, cx);
    float p = -2.76076847742355e-16f;
    p = __fadd_rn(__fmul_rn(p, x2), 2.00018790482477e-13f);
    p = __fadd_rn(__fmul_rn(p, x2), -8.60467152213735e-11f);
    p = __fadd_rn(__fmul_rn(p, x2), 5.12229709037114e-08f);
    p = __fadd_rn(__fmul_rn(p, x2), 1.48572235717979e-05f);
    p = __fadd_rn(__fmul_rn(p, x2), 6.37261928875436e-04f);
    p = __fadd_rn(__fmul_rn(p, x2), 4.89352455891786e-03f);
    const float num = __fmul_rn(cx, p);
    float q = 1.19825839466702e-06f;
    q = __fadd_rn(__fmul_rn(q, x2), 1.18534705686654e-04f);
    q = __fadd_rn(__fmul_rn(q, x2), 2.26843463243900e-03f);
    q = __fadd_rn(__fmul_rn(q, x2), 4.89352518554385e-03f);
    const float r = __fdiv_rn(num, q);
    return (fabsf(x) < 0.0004f) ? x : r;
}

// Map a packed chunk-row m -> global action row:
//   b = m >> chsh (CH = chm1+1), global row = b*SS + i0 + (m & chm1)
__device__ __forceinline__ int arow_map(int m, int chm1, int chsh, int i0) {
    return ((m >> chsh) * SS) + i0 + (m & chm1);
}

// ---------------------------------------------------------------------------
// Tiled GEMM, bitwise-preserving XLA-CPU dot semantics (VERIFIED r6..r23 —
// scalar v_mul/v_add only). K-chain: one accumulator per element, k0 tiles
// ascend, inner k ascends — DO NOT TOUCH.
//
// r22 (KEPT VERBATIM — measured AT the scalar-VALU floor: 433-437 us/chunk
// vs 437 us computed; bank conflicts 5.87e7 -> 8.4e6):
//   * LDS rows padded 128 -> 132 floats (4-way -> 2-way write conflicts).
//   * b-columns strided: thread tx reads Bs[k][tx*4], Bs[k][64+tx*4].
//     Epilogue remapped to match: j<4 -> c=tx*4+j, j>=4 -> c=64+tx*4+(j-4).
//
// TRANSP=1 (GEMM2 only): block bx covers B-rows o = d*128+e with
// d in [16*bd,16*bd+16), e in [8*be,8*be+8)  (bd=bx>>4, be=bx&15).
// Epilogue stores the d-INTERLEAVED layout:
//   Wa4[m][(d>>2)*128 + e] as float4 component (d&3)
// so the scan's quarter loads are lane-consecutive float4 (r15-proven).
// ---------------------------------------------------------------------------
template <int ACT, int MAPROW, int TRANSP>
__global__ __launch_bounds__(256) void gemm_nt(const float* __restrict__ A,
                                               const float* __restrict__ Bm,
                                               const float* __restrict__ bias,
                                               float* __restrict__ C,
                                               int N, int K,
                                               int chm1, int chsh, int i0) {
    __shared__ float As[16][132];   // +4 pad: kills 4-way write conflicts
    __shared__ float Bs[16][132];

    const int tid = threadIdx.x;
    const int tx = tid & 15;   // n-direction (8 cols each, strided mapping)
    const int ty = tid >> 4;   // m-direction (8 rows each)
    const int n0 = blockIdx.x * 128;
    const int m0 = blockIdx.y * 128;
    const int bd = blockIdx.x >> 4;   // TRANSP: d-tile (0..7)
    const int be = blockIdx.x & 15;   // TRANSP: e-tile (0..15)

    const int lr = tid >> 2;          // 0..63 (row within tile)
    const int lc = (tid & 3) << 2;    // 0,4,8,12 (col within K-tile)

    const int ga0 = MAPROW ? arow_map(m0 + lr, chm1, chsh, i0) : (m0 + lr);
    const int ga1 = MAPROW ? arow_map(m0 + lr + 64, chm1, chsh, i0) : (m0 + lr + 64);

    // B-row indices for the two loader rows (identity unless TRANSP)
    const int r0 = lr, r1 = lr + 64;
    const int gb0 = TRANSP ? ((bd * 16 + (r0 >> 3)) * 128 + be * 8 + (r0 & 7))
                           : (n0 + r0);
    const int gb1 = TRANSP ? ((bd * 16 + (r1 >> 3)) * 128 + be * 8 + (r1 & 7))
                           : (n0 + r1);

    float acc[8][8];
#pragma unroll
    for (int i = 0; i < 8; ++i)
#pragma unroll
        for (int j = 0; j < 8; ++j) acc[i][j] = 0.f;

    for (int k0 = 0; k0 < K; k0 += 16) {
        const float4 a0 = *(const float4*)(A + (size_t)ga0 * K + (k0 + lc));
        const float4 a1 = *(const float4*)(A + (size_t)ga1 * K + (k0 + lc));
        const float4 b0 = *(const float4*)(Bm + (size_t)gb0 * K + (k0 + lc));
        const float4 b1 = *(const float4*)(Bm + (size_t)gb1 * K + (k0 + lc));

        __syncthreads();  // previous iteration's compute done before overwrite

        As[lc + 0][lr] = a0.x; As[lc + 1][lr] = a0.y;
        As[lc + 2][lr] = a0.z; As[lc + 3][lr] = a0.w;
        As[lc + 0][lr + 64] = a1.x; As[lc + 1][lr + 64] = a1.y;
        As[lc + 2][lr + 64] = a1.z; As[lc + 3][lr + 64] = a1.w;
        Bs[lc + 0][lr] = b0.x; Bs[lc + 1][lr] = b0.y;
        Bs[lc + 2][lr] = b0.z; Bs[lc + 3][lr] = b0.w;
        Bs[lc + 0][lr + 64] = b1.x; Bs[lc + 1][lr + 64] = b1.y;
        Bs[lc + 2][lr + 64] = b1.z; Bs[lc + 3][lr + 64] = b1.w;

        __syncthreads();

#pragma unroll
        for (int k = 0; k < 16; ++k) {   // ascending k within tile
            const float4 av0 = *(const float4*)&As[k][ty * 8];
            const float4 av1 = *(const float4*)&As[k][ty * 8 + 4];
            const float4 bv0 = *(const float4*)&Bs[k][tx * 4];        // strided
            const float4 bv1 = *(const float4*)&Bs[k][64 + tx * 4];   // strided
            const float a[8] = {av0.x, av0.y, av0.z, av0.w, av1.x, av1.y, av1.z, av1.w};
            const float b[8] = {bv0.x, bv0.y, bv0.z, bv0.w, bv1.x, bv1.y, bv1.z, bv1.w};
#pragma unroll
            for (int i = 0; i < 8; ++i)
#pragma unroll
                for (int j = 0; j < 8; ++j)
                    acc[i][j] = __fadd_rn(acc[i][j], __fmul_rn(a[i], b[j]));
        }
    }

    // epilogue: + bias (after full k-chain), optional XLA tanh, store.
    // acc[i][j] is output col c = (j<4) ? tx*4+j : 64+tx*4+(j-4) of the tile.
#pragma unroll
    for (int i = 0; i < 8; ++i) {
        const int m = m0 + ty * 8 + i;
        if (TRANSP) {
            // in-tile col c -> o = d*128+ee, d = bd*16+(c>>3), ee = be*8+(c&7)
            // d-interleaved store: C[m][((d>>2)*128 + ee)*4 + (d&3)]
#pragma unroll
            for (int j = 0; j < 8; ++j) {
                const int c = (j < 4) ? (tx * 4 + j) : (64 + tx * 4 + (j - 4));
                const int d = bd * 16 + (c >> 3);
                const int ee = be * 8 + (c & 7);
                const int o = d * 128 + ee;
                const float v = __fadd_rn(acc[i][j], bias[o]);
                C[(size_t)m * N + ((size_t)(d >> 2) * 128 + ee) * 4 + (d & 3)] = v;
            }
        } else {
            float v[8];
#pragma unroll
            for (int j = 0; j < 4; ++j) {
                const int n = n0 + tx * 4 + j;
                v[j] = __fadd_rn(acc[i][j], bias[n]);
                if (ACT) v[j] = xla_tanhf(v[j]);
            }
#pragma unroll
            for (int j = 4; j < 8; ++j) {
                const int n = n0 + 64 + tx * 4 + (j - 4);
                v[j] = __fadd_rn(acc[i][j], bias[n]);
                if (ACT) v[j] = xla_tanhf(v[j]);
            }
            *(float4*)(C + (size_t)m * N + (n0 + tx * 4)) =
                make_float4(v[0], v[1], v[2], v[3]);
            *(float4*)(C + (size_t)m * N + (n0 + 64 + tx * 4)) =
                make_float4(v[4], v[5], v[6], v[7]);
        }
    }
}

// ---------------------------------------------------------------------------
// r21-proven non-draining workgroup barrier (validated correct, absmax 0.0):
// __syncthreads() emits `s_waitcnt vmcnt(0) lgkmcnt(0)` before s_barrier,
// draining the whole prefetch queue each step. The scan's ping-pong only
// needs LDS ordering: ds_write et -> s_waitcnt lgkmcnt(0) -> s_barrier.
// VGPR-targeted prefetch loads are guarded by the compiler's precise
// vmcnt(N) waits at their consume sites.
// ---------------------------------------------------------------------------
__device__ __forceinline__ void scan_barrier_nodrain() {
    asm volatile("s_waitcnt lgkmcnt(0)" ::: "memory");
    __builtin_amdgcn_s_barrier();
    asm volatile("" ::: "memory");
}

// ---------------------------------------------------------------------------
// Sequential attractor scan — r24.
// Evidence (r20/r21/r22/r23): prefetch distance 3 < 6 < 8 monotonically in
// time — at distance 3 a refill is issued ~1800 device-cycles before its
// consume (>> any memory latency), so refill latency is fully covered and
// deeper pipelines only add per-wave in-flight VMEM pressure. Distance 3 is
// the optimum of this structure — FROZEN (4 buffers, clamped straight-line
// refill, nodrain barrier).
// r24 lever: the ~1850 cyc/step of non-chain time is dominated by the 32
// per-quarter ds_read_b128 of et[s] woven INTO the chain — each is consumed
// within a few instructions of issue, exposing a large slice of the ~120 cyc
// LDS latency per read (m134). Fix: bulk-load all 32 et float4s into
// registers (tt[0..31], static indices) right after the barrier, pinned by a
// memory clobber; the chain then runs with ZERO mid-chain lgkm waits.
// Chain is op-for-op the verified sequence: ONE accumulator, strictly
// ascending d (q asc, dq asc, x,y,z,w = d..d+3), non-fused rn ops — bitwise
// contract (only the et operand's storage location changes: LDS -> VGPR).
// VGPR: 128 (w0..w3) + 128 (tt) + ~30 misc ≈ 290 (1 block/CU, 512 budget;
// VGPR_Count < 256 = spill signature).
// ---------------------------------------------------------------------------
#define SCAN_QUARTER(Q, WC, WP)                                             \
    {                                                                       \
        /* UNCONDITIONAL refill (clamped): straight-line loads ->           \
           precise vmcnt. Clamped (pf>=nq) loads land in buffers never      \
           consumed. */                                                     \
        const int pf = (ii - start) * 4 + (Q) + 3;                          \
        const int pfc = (pf < nq) ? pf : (nq - 1); /* uniform select */     \
        const float4* P4 = Wb4 + (size_t)(start + (pfc >> 2)) * 4096        \
                               + (size_t)(pfc & 3) * 1024 + e;              \
        _Pragma("unroll")                                                   \
        for (int u = 0; u < 8; ++u) WP[u] = P4[u * 128];                    \
        asm volatile("" ::: "memory");                                      \
        /* consume quarter Q: d = 32Q .. 32Q+31, strictly ascending;        \
           et operands come from registers tt[] (bulk-loaded at step top) */\
        _Pragma("unroll")                                                   \
        for (int dq = 0; dq < 8; ++dq) {                                    \
            const float4 t4 = tt[(Q) * 8 + dq];                             \
            const float4 wv = WC[dq]; /* W[d..d+3][e], d = 32Q+4dq */       \
            sum = __fadd_rn(sum, __fmul_rn(t4.x, wv.x));                    \
            sum = __fadd_rn(sum, __fmul_rn(t4.y, wv.y));                    \
            sum = __fadd_rn(sum, __fmul_rn(t4.z, wv.z));                    \
            sum = __fadd_rn(sum, __fmul_rn(t4.w, wv.w));                    \
        }                                                                   \
    }

__global__ __launch_bounds__(128, 1) void scan_kernel(const float* __restrict__ Wa,
                                                      const float* __restrict__ e0,
                                                      float* __restrict__ et_state,
                                                      float* __restrict__ out,
                                                      int i0, int CH) {
    __shared__ float et[2][128];
    const int b = blockIdx.x;
    const int e = threadIdx.x;  // 0..127

    int s = 0;
    if (i0 == 0) {
        const float v = e0[e];
        et[0][e] = v;
        out[(size_t)b * SS * ENC + e] = v;
    } else {
        et[0][e] = et_state[b * 128 + e];
    }
    __syncthreads();   // once, before the pipeline — drain is harmless here

    const int start = (i0 == 0) ? 1 : 0;
    const float4* Wb4 = (const float4*)(Wa + (size_t)b * CH * (ENC * ENC));
    const int nq = (CH - start) * 4;   // total quarter-tiles this launch
    // step stride in float4: ENC*ENC/4 = 4096; quarter stride: 8*128 = 1024

    // 4 quarter buffers x 8 float4 = 128 VGPRs (r13-proven distance 3)
    float4 w0[8], w1[8], w2[8], w3[8];

    // preload quarters 0,1,2 of step `start`
    {
        const float4* S4 = Wb4 + (size_t)start * 4096 + e;
#pragma unroll
        for (int u = 0; u < 8; ++u) w0[u] = S4[u * 128];
#pragma unroll
        for (int u = 0; u < 8; ++u) w1[u] = S4[(8 + u) * 128];
#pragma unroll
        for (int u = 0; u < 8; ++u) w2[u] = S4[(16 + u) * 128];
    }
    asm volatile("" ::: "memory");  // loads pinned before first chain

    for (int ii = start; ii < CH; ++ii) {
        // r24: bulk et load — issue ALL 32 ds_read_b128 back-to-back into
        // registers (static indices), pinned before the chain. The reads
        // pipeline (~120 cyc initial + ~12 cyc/read); the compiler's
        // progressive lgkmcnt waits overlap them with the early chain.
        float4 tt[32];
#pragma unroll
        for (int t = 0; t < 32; ++t)
            tt[t] = *(const float4*)&et[s][t * 4];
        asm volatile("" ::: "memory");  // LDS reads issued before chain

        float sum = 0.f;   // ONE accumulator, ascending d across all quarters
        SCAN_QUARTER(0, w0, w3)   // consume q0, refill buffer (0+3)&3=3
        SCAN_QUARTER(1, w1, w0)
        SCAN_QUARTER(2, w2, w1)
        SCAN_QUARTER(3, w3, w2)
        const float v = fminf(fmaxf(sum, -5.f), 5.f);  // jnp.clip
        out[((size_t)b * SS + (i0 + ii)) * ENC + e] = v;
        et[s ^ 1][e] = v;   // this step's readers use et[s] — no conflict
        scan_barrier_nodrain();  // publishes et[s^1]; keeps vmcnt queue alive
        s ^= 1;
    }
    et_state[b * 128 + e] = et[s][e];
}

// ---------------------------------------------------------------------------
extern "C" void kernel_launch(void* const* d_in, const int* in_sizes, int n_in,
                              void* d_out, int out_size, void* d_ws, size_t ws_size,
                              hipStream_t stream) {
    const float* A  = (const float*)d_in[0];  // (B,S,E)   = (8,512,128) fp32
    const float* W1 = (const float*)d_in[1];  // (H,E)     = (512,128)  fp32
    const float* b1 = (const float*)d_in[2];  // (H,)      fp32
    const float* W2 = (const float*)d_in[3];  // (ENC*ENC,H) = (16384,512) fp32
    const float* b2 = (const float*)d_in[4];  // (ENC*ENC,) fp32
    const float* e0 = (const float*)d_in[5];  // (1,ENC)   fp32
    float* out = (float*)d_out;               // (B,S,ENC) fp32

    // Serial r16 schedule (known-good base).
    // Pick the largest chunk CH (steps) whose fp32 workspace fits ws_size.
    // ws layout: [et_state 4KB][hidden_c Mc*512 f32][Wa_c Mc*16384 f32]
    int CH = 16;
    for (int c = 512; c >= 16; c >>= 1) {
        const size_t Mc = (size_t)BB * c;
        const size_t need = 4096 + Mc * HH * sizeof(float) +
                            Mc * (size_t)(ENC * ENC) * sizeof(float);
        if (need <= ws_size) { CH = c; break; }
    }
    const int Mc = BB * CH;
    int chsh = 0;
    while ((1 << chsh) < CH) ++chsh;
    const int chm1 = CH - 1;

    float* et_state = (float*)d_ws;
    float* hidden   = (float*)((char*)d_ws + 4096);
    float* Wa       = hidden + (size_t)Mc * HH;   // d-interleaved layout (Wa4)

    for (int i0 = 0; i0 < SS; i0 += CH) {
        // GEMM1: hidden_c = tanh(A[chunk rows] @ W1^T + b1)  [Mc x 512, K=128]
        dim3 g1(HH / 128, Mc / 128);
        gemm_nt<1, 1, 0><<<g1, 256, 0, stream>>>(A, W1, b1, hidden, HH, EE,
                                                 chm1, chsh, i0);
        // GEMM2: Wa4_c = (hidden_c @ W2^T + b2) stored d-interleaved
        dim3 g2((ENC * ENC) / 128, Mc / 128);
        gemm_nt<0, 0, 1><<<g2, 256, 0, stream>>>(hidden, W2, b2, Wa, ENC * ENC,
                                                 HH, 0, 0, 0);
        // scan this chunk (one workgroup per batch; fp32 state in ws)
        scan_kernel<<<BB, 128, 0, stream>>>(Wa, e0, et_state, out, i0, CH);
    }
}

// Round 10
// 1451.849 us; speedup vs baseline: 1.0326x; 1.0198x over previous
//
#include <hip/hip_runtime.h>
#include <cstddef>

// Problem constants (reference: B=8, S=512, E=128, H=512, ENC=128)
#define BB 8
#define SS 512
#define EE 128
#define HH 512
#define ENC 128

// ---------------------------------------------------------------------------
// Bit-exact emulation of XLA CPU's EmitTanh (verified bitwise r6..r15).
// All ops rn, NON-fused. __f*_rn intrinsics block compiler contraction.
// NOTE (r8): packed v_pk_* fp32 is NOT bit-identical on gfx950 — scalar only.
// ---------------------------------------------------------------------------
__device__ __forceinline__ float xla_tanhf(float x) {
    const float cx = fminf(fmaxf(x, -9.0f), 9.0f);
    const float x2 = __fmul_rn(cx, cx);
    float p = -2.76076847742355e-16f;
    p = __fadd_rn(__fmul_rn(p, x2), 2.00018790482477e-13f);
    p = __fadd_rn(__fmul_rn(p, x2), -8.60467152213735e-11f);
    p = __fadd_rn(__fmul_rn(p, x2), 5.12229709037114e-08f);
    p = __fadd_rn(__fmul_rn(p, x2), 1.48572235717979e-05f);
    p = __fadd_rn(__fmul_rn(p, x2), 6.37261928875436e-04f);
    p = __fadd_rn(__fmul_rn(p, x2), 4.89352455891786e-03f);
    const float num = __fmul_rn(cx, p);
    float q = 1.19825839466702e-06f;
    q = __fadd_rn(__fmul_rn(q, x2), 1.18534705686654e-04f);
    q = __fadd_rn(__fmul_rn(q, x2), 2.26843463243900e-03f);
    q = __fadd_rn(__fmul_rn(q, x2), 4.89352518554385e-03f);
    const float r = __fdiv_rn(num, q);
    return (fabsf(x) < 0.0004f) ? x : r;
}

// Map a packed chunk-row m -> global action row:
//   b = m >> chsh (CH = chm1+1), global row = b*SS + i0 + (m & chm1)
__device__ __forceinline__ int arow_map(int m, int chm1, int chsh, int i0) {
    return ((m >> chsh) * SS) + i0 + (m & chm1);
}

// ---------------------------------------------------------------------------
// Tiled GEMM, bitwise-preserving XLA-CPU dot semantics (VERIFIED r6..r24 —
// scalar v_mul/v_add only). K-chain: one accumulator per element, k0 tiles
// ascend, inner k ascends — DO NOT TOUCH.
//
// r22 (KEPT VERBATIM — measured AT the scalar-VALU floor: 433-437 us/chunk
// vs 437 us computed; bank conflicts 5.87e7 -> 8.4e6):
//   * LDS rows padded 128 -> 132 floats (4-way -> 2-way write conflicts).
//   * b-columns strided: thread tx reads Bs[k][tx*4], Bs[k][64+tx*4].
//     Epilogue remapped to match: j<4 -> c=tx*4+j, j>=4 -> c=64+tx*4+(j-4).
//
// TRANSP=1 (GEMM2 only): block bx covers B-rows o = d*128+e with
// d in [16*bd,16*bd+16), e in [8*be,8*be+8)  (bd=bx>>4, be=bx&15).
// Epilogue stores the d-INTERLEAVED layout:
//   Wa4[m][(d>>2)*128 + e] as float4 component (d&3)
// so the scan's quarter loads are lane-consecutive float4 (r15-proven).
// ---------------------------------------------------------------------------
template <int ACT, int MAPROW, int TRANSP>
__global__ __launch_bounds__(256) void gemm_nt(const float* __restrict__ A,
                                               const float* __restrict__ Bm,
                                               const float* __restrict__ bias,
                                               float* __restrict__ C,
                                               int N, int K,
                                               int chm1, int chsh, int i0) {
    __shared__ float As[16][132];   // +4 pad: kills 4-way write conflicts
    __shared__ float Bs[16][132];

    const int tid = threadIdx.x;
    const int tx = tid & 15;   // n-direction (8 cols each, strided mapping)
    const int ty = tid >> 4;   // m-direction (8 rows each)
    const int n0 = blockIdx.x * 128;
    const int m0 = blockIdx.y * 128;
    const int bd = blockIdx.x >> 4;   // TRANSP: d-tile (0..7)
    const int be = blockIdx.x & 15;   // TRANSP: e-tile (0..15)

    const int lr = tid >> 2;          // 0..63 (row within tile)
    const int lc = (tid & 3) << 2;    // 0,4,8,12 (col within K-tile)

    const int ga0 = MAPROW ? arow_map(m0 + lr, chm1, chsh, i0) : (m0 + lr);
    const int ga1 = MAPROW ? arow_map(m0 + lr + 64, chm1, chsh, i0) : (m0 + lr + 64);

    // B-row indices for the two loader rows (identity unless TRANSP)
    const int r0 = lr, r1 = lr + 64;
    const int gb0 = TRANSP ? ((bd * 16 + (r0 >> 3)) * 128 + be * 8 + (r0 & 7))
                           : (n0 + r0);
    const int gb1 = TRANSP ? ((bd * 16 + (r1 >> 3)) * 128 + be * 8 + (r1 & 7))
                           : (n0 + r1);

    float acc[8][8];
#pragma unroll
    for (int i = 0; i < 8; ++i)
#pragma unroll
        for (int j = 0; j < 8; ++j) acc[i][j] = 0.f;

    for (int k0 = 0; k0 < K; k0 += 16) {
        const float4 a0 = *(const float4*)(A + (size_t)ga0 * K + (k0 + lc));
        const float4 a1 = *(const float4*)(A + (size_t)ga1 * K + (k0 + lc));
        const float4 b0 = *(const float4*)(Bm + (size_t)gb0 * K + (k0 + lc));
        const float4 b1 = *(const float4*)(Bm + (size_t)gb1 * K + (k0 + lc));

        __syncthreads();  // previous iteration's compute done before overwrite

        As[lc + 0][lr] = a0.x; As[lc + 1][lr] = a0.y;
        As[lc + 2][lr] = a0.z; As[lc + 3][lr] = a0.w;
        As[lc + 0][lr + 64] = a1.x; As[lc + 1][lr + 64] = a1.y;
        As[lc + 2][lr + 64] = a1.z; As[lc + 3][lr + 64] = a1.w;
        Bs[lc + 0][lr] = b0.x; Bs[lc + 1][lr] = b0.y;
        Bs[lc + 2][lr] = b0.z; Bs[lc + 3][lr] = b0.w;
        Bs[lc + 0][lr + 64] = b1.x; Bs[lc + 1][lr + 64] = b1.y;
        Bs[lc + 2][lr + 64] = b1.z; Bs[lc + 3][lr + 64] = b1.w;

        __syncthreads();

#pragma unroll
        for (int k = 0; k < 16; ++k) {   // ascending k within tile
            const float4 av0 = *(const float4*)&As[k][ty * 8];
            const float4 av1 = *(const float4*)&As[k][ty * 8 + 4];
            const float4 bv0 = *(const float4*)&Bs[k][tx * 4];        // strided
            const float4 bv1 = *(const float4*)&Bs[k][64 + tx * 4];   // strided
            const float a[8] = {av0.x, av0.y, av0.z, av0.w, av1.x, av1.y, av1.z, av1.w};
            const float b[8] = {bv0.x, bv0.y, bv0.z, bv0.w, bv1.x, bv1.y, bv1.z, bv1.w};
#pragma unroll
            for (int i = 0; i < 8; ++i)
#pragma unroll
                for (int j = 0; j < 8; ++j)
                    acc[i][j] = __fadd_rn(acc[i][j], __fmul_rn(a[i], b[j]));
        }
    }

    // epilogue: + bias (after full k-chain), optional XLA tanh, store.
    // acc[i][j] is output col c = (j<4) ? tx*4+j : 64+tx*4+(j-4) of the tile.
#pragma unroll
    for (int i = 0; i < 8; ++i) {
        const int m = m0 + ty * 8 + i;
        if (TRANSP) {
            // in-tile col c -> o = d*128+ee, d = bd*16+(c>>3), ee = be*8+(c&7)
            // d-interleaved store: C[m][((d>>2)*128 + ee)*4 + (d&3)]
#pragma unroll
            for (int j = 0; j < 8; ++j) {
                const int c = (j < 4) ? (tx * 4 + j) : (64 + tx * 4 + (j - 4));
                const int d = bd * 16 + (c >> 3);
                const int ee = be * 8 + (c & 7);
                const int o = d * 128 + ee;
                const float v = __fadd_rn(acc[i][j], bias[o]);
                C[(size_t)m * N + ((size_t)(d >> 2) * 128 + ee) * 4 + (d & 3)] = v;
            }
        } else {
            float v[8];
#pragma unroll
            for (int j = 0; j < 4; ++j) {
                const int n = n0 + tx * 4 + j;
                v[j] = __fadd_rn(acc[i][j], bias[n]);
                if (ACT) v[j] = xla_tanhf(v[j]);
            }
#pragma unroll
            for (int j = 4; j < 8; ++j) {
                const int n = n0 + 64 + tx * 4 + (j - 4);
                v[j] = __fadd_rn(acc[i][j], bias[n]);
                if (ACT) v[j] = xla_tanhf(v[j]);
            }
            *(float4*)(C + (size_t)m * N + (n0 + tx * 4)) =
                make_float4(v[0], v[1], v[2], v[3]);
            *(float4*)(C + (size_t)m * N + (n0 + 64 + tx * 4)) =
                make_float4(v[4], v[5], v[6], v[7]);
        }
    }
}

// ---------------------------------------------------------------------------
// r26: producer-consumer scan (r25 theory, STATIC-LDS hardening).
// r25's bench died in infra; the only kernel-side suspect was the dynamic-LDS
// >64KB path (hipFuncSetAttribute inside graph capture + 132 KB sharedMemBytes
// launch arg). r26 removes that mechanism: the 132 KB slab is STATIC
// __shared__ (proven on gfx950: m201 example = 128 KiB, AITER = 160 KB).
//
// Evidence r20-r24: the scan is fetch-capacity-bound — 64 KB/step through one
// CU at ~27 B/cyc effective; deeper per-wave queues stall at ISSUE (r23/r20
// monotone worse); LDS-read hoisting null (r24). Structural fix: role-split.
//   * tid <128 (2 compute waves): pure VALU+LDS chain — ZERO VMEM. W from
//     LDS slab (contiguous ds_read_b128, conflict-free: lanes hit distinct
//     bank pairs), et via same-address broadcast reads.
//   * tid>=128 (2 fetch waves): per step, 32 back-to-back global_load_lds
//     (16B/lane, 1 KB/instr) stream the NEXT step's 64 KB slab into the
//     other buffer, then ONE s_waitcnt vmcnt(0) — a single latency exposure
//     per step, hidden under the compute waves' chain.
//   * One convergent s_barrier per step; role-specific waits before it
//     (compute: lgkmcnt(0) for the et ds_write; fetch: vmcnt(0) for slab).
// global_load_lds: LDS dest = wave-uniform base + lane*16 (linear slab copy,
// LDSfloat4[i] == Wstep4[i]); global source per-lane. Last step clamps to
// CH-1 (reloads current slab into the dead buffer — never read).
// Chain is op-for-op the verified sequence: ONE accumulator, strictly
// ascending d (q asc, u asc, x,y,z,w = d..d+3), non-fused rn ops — bitwise
// contract (only W's storage location changes: global -> LDS).
// VGPR: compute ~60, fetch ~20 — register fragility of r17-r24 is gone.
// ---------------------------------------------------------------------------
#define GLD_LDS16(G, L)                                                     \
    __builtin_amdgcn_global_load_lds(                                       \
        (const __attribute__((address_space(1))) void*)(G),                 \
        (__attribute__((address_space(3))) void*)(L), 16, 0, 0)

__global__ __launch_bounds__(256, 1) void scan_pc(const float* __restrict__ Wa,
                                                  const float* __restrict__ e0,
                                                  float* __restrict__ et_state,
                                                  float* __restrict__ out,
                                                  int i0, int CH) {
    __shared__ float W0f[16384];   // 64 KB: W slab buffer 0
    __shared__ float W1f[16384];   // 64 KB: W slab buffer 1
    __shared__ float etb[256];     // et ping-pong [2][128]

    const int b = blockIdx.x;
    const int tid = threadIdx.x;
    const int start = (i0 == 0) ? 1 : 0;
    const float4* Wb4 = (const float4*)(Wa + (size_t)b * CH * (ENC * ENC));
    // step slab = 4096 float4 (64 KB); LDS slab is a LINEAR copy of it.

    // ---- prologue: et init (compute waves) + W(start) fetch (fetch waves)
    if (tid < 128) {
        const int e = tid;
        if (i0 == 0) {
            const float v = e0[e];
            etb[e] = v;
            out[(size_t)b * SS * ENC + e] = v;
        } else {
            etb[e] = et_state[b * 128 + e];
        }
    } else {
        const int w = (tid >> 6) & 1;   // fetch wave 0/1
        const int lane = tid & 63;
        const float4* src = Wb4 + (size_t)start * 4096;
#pragma unroll
        for (int k = 0; k < 32; ++k) {
            const int seg = w * 32 + k;             // 0..63
            GLD_LDS16(src + seg * 64 + lane, W0f + seg * 256);
        }
        asm volatile("s_waitcnt vmcnt(0)" ::: "memory");
    }
    __syncthreads();   // once; full drain harmless here

    int s = 0;
    for (int ii = start; ii < CH; ++ii) {
        if (tid < 128) {
            // ---- compute: pure VALU + LDS. Wc = current slab, etc = state.
            const int e = tid;
            const float* Wc = s ? W1f : W0f;
            const float* etc = etb + s * 128;
            float sum = 0.f;   // ONE accumulator, ascending d
#pragma unroll
            for (int q = 0; q < 4; ++q) {
                float4 wv[8];
#pragma unroll
                for (int u = 0; u < 8; ++u)
                    wv[u] = *(const float4*)&Wc[(q * 1024 + u * 128 + e) * 4];
#pragma unroll
                for (int u = 0; u < 8; ++u) {
                    // et: uniform address across lanes -> LDS broadcast
                    const float4 t4 = *(const float4*)&etc[q * 32 + u * 4];
                    const float4 x = wv[u];   // W[d..d+3][e], d = 32q+4u
                    sum = __fadd_rn(sum, __fmul_rn(t4.x, x.x));
                    sum = __fadd_rn(sum, __fmul_rn(t4.y, x.y));
                    sum = __fadd_rn(sum, __fmul_rn(t4.z, x.z));
                    sum = __fadd_rn(sum, __fmul_rn(t4.w, x.w));
                }
            }
            const float v = fminf(fmaxf(sum, -5.f), 5.f);  // jnp.clip
            out[((size_t)b * SS + (i0 + ii)) * ENC + e] = v;
            etb[(s ^ 1) * 128 + e] = v;
            asm volatile("s_waitcnt lgkmcnt(0)" ::: "memory");
        } else {
            // ---- fetch: next step's slab into the other buffer (clamped).
            const int w = (tid >> 6) & 1;
            const int lane = tid & 63;
            const int nxt = (ii + 1 < CH) ? (ii + 1) : (CH - 1);
            const float4* src = Wb4 + (size_t)nxt * 4096;
            float* Wn = s ? W0f : W1f;
#pragma unroll
            for (int k = 0; k < 32; ++k) {
                const int seg = w * 32 + k;
                GLD_LDS16(src + seg * 64 + lane, Wn + seg * 256);
            }
            asm volatile("s_waitcnt vmcnt(0)" ::: "memory");
        }
        __builtin_amdgcn_s_barrier();   // single convergent barrier per step
        asm volatile("" ::: "memory");
        s ^= 1;
    }
    if (tid < 128) et_state[b * 128 + tid] = etb[s * 128 + tid];
}

// ---------------------------------------------------------------------------
extern "C" void kernel_launch(void* const* d_in, const int* in_sizes, int n_in,
                              void* d_out, int out_size, void* d_ws, size_t ws_size,
                              hipStream_t stream) {
    const float* A  = (const float*)d_in[0];  // (B,S,E)   = (8,512,128) fp32
    const float* W1 = (const float*)d_in[1];  // (H,E)     = (512,128)  fp32
    const float* b1 = (const float*)d_in[2];  // (H,)      fp32
    const float* W2 = (const float*)d_in[3];  // (ENC*ENC,H) = (16384,512) fp32
    const float* b2 = (const float*)d_in[4];  // (ENC*ENC,) fp32
    const float* e0 = (const float*)d_in[5];  // (1,ENC)   fp32
    float* out = (float*)d_out;               // (B,S,ENC) fp32

    // Serial r16 schedule (known-good base).
    // Pick the largest chunk CH (steps) whose fp32 workspace fits ws_size.
    // ws layout: [et_state 4KB][hidden_c Mc*512 f32][Wa_c Mc*16384 f32]
    int CH = 16;
    for (int c = 512; c >= 16; c >>= 1) {
        const size_t Mc = (size_t)BB * c;
        const size_t need = 4096 + Mc * HH * sizeof(float) +
                            Mc * (size_t)(ENC * ENC) * sizeof(float);
        if (need <= ws_size) { CH = c; break; }
    }
    const int Mc = BB * CH;
    int chsh = 0;
    while ((1 << chsh) < CH) ++chsh;
    const int chm1 = CH - 1;

    float* et_state = (float*)d_ws;
    float* hidden   = (float*)((char*)d_ws + 4096);
    float* Wa       = hidden + (size_t)Mc * HH;   // d-interleaved layout (Wa4)

    for (int i0 = 0; i0 < SS; i0 += CH) {
        // GEMM1: hidden_c = tanh(A[chunk rows] @ W1^T + b1)  [Mc x 512, K=128]
        dim3 g1(HH / 128, Mc / 128);
        gemm_nt<1, 1, 0><<<g1, 256, 0, stream>>>(A, W1, b1, hidden, HH, EE,
                                                 chm1, chsh, i0);
        // GEMM2: Wa4_c = (hidden_c @ W2^T + b2) stored d-interleaved
        dim3 g2((ENC * ENC) / 128, Mc / 128);
        gemm_nt<0, 0, 1><<<g2, 256, 0, stream>>>(hidden, W2, b2, Wa, ENC * ENC,
                                                 HH, 0, 0, 0);
        // scan this chunk: producer-consumer kernel, 132 KB STATIC LDS
        scan_pc<<<BB, 256, 0, stream>>>(Wa, e0, et_state, out, i0, CH);
    }
}